// Round 6
// baseline (316.271 us; speedup 1.0000x reference)
//
#include <hip/hip_runtime.h>
#include <math.h>

#define Bn 512
#define Tn 1024
#define Nn 64
#define LOG2E_F 1.44269504088896340736f
#define LN2_F   0.69314718055994530942f

__device__ __forceinline__ float wave_max(float v) {
    #pragma unroll
    for (int o = 32; o > 0; o >>= 1) v = fmaxf(v, __shfl_xor(v, o));
    return v;
}
__device__ __forceinline__ float wave_sum(float v) {
    #pragma unroll
    for (int o = 32; o > 0; o >>= 1) v += __shfl_xor(v, o);
    return v;
}

// ---------------------------------------------------------------------------
// Kernel: forward/backward halves of the linear recursion in exp-space.
//   fwd: q'_o = ex_o * sum_i q_i E[i][o]
//   bwd: q'_o = sum_i (ex*q)_i E[o][i]
//
// R5 post-mortem: permlane32_swap+select REGRESSED (146.6->157us, +49cyc/step)
// -> reverted to __shfl_xor (R4's measured-best step). R6 experiment: the
// constant ~150-170us total-vs-fwdbwd gap across R1-R5 is either crf_scores
// hiding just below the top-5 cutoff or harness overhead. Fuse scores into
// the fwd blocks (16 independent gather iters, issued before E-setup, ~1-2us)
// and DELETE the crf_scores dispatch: total ~175 -> gap was scores;
// total ~300 -> gap is harness, fwdbwd is the only target.
//
// Serial-chain budget (R4 counters: 687 cyc/step, VALUBusy 24%):
//   ds_write->ds_read data ~140 | 8x ds_read_b128 pipe ~100 |
//   64 FMA issue ~128 | shfl_xor(32) ~110 | mul/exp/misc ~100-200
// ---------------------------------------------------------------------------

// one recursion step; exact fp32. Single wave: LDS queue is in-order per
// wave, so write -> reads needs no barrier.
#define STEP2(BWDV, EXV) do {                                      \
    shq[j] = (BWDV) ? ((EXV) * q) : q;                             \
    float4 _qv[8];                                                 \
    _Pragma("unroll")                                              \
    for (int _cb = 0; _cb < 8; ++_cb)                              \
        _qv[_cb] = *(const float4*)&shq[(g << 5) + (_cb << 2)];    \
    float _aP0 = 0.f, _aP1 = 0.f, _aQ0 = 0.f, _aQ1 = 0.f;         \
    _Pragma("unroll")                                              \
    for (int _cb = 0; _cb < 8; _cb += 2) {                         \
        const float4 _u0 = _qv[_cb], _u1 = _qv[_cb + 1];           \
        _aP0 = fmaf(_u0.x, Ef[4*_cb + 0], _aP0);                   \
        _aQ0 = fmaf(_u0.x, Ef[32 + 4*_cb + 0], _aQ0);              \
        _aP0 = fmaf(_u0.y, Ef[4*_cb + 1], _aP0);                   \
        _aQ0 = fmaf(_u0.y, Ef[32 + 4*_cb + 1], _aQ0);              \
        _aP0 = fmaf(_u0.z, Ef[4*_cb + 2], _aP0);                   \
        _aQ0 = fmaf(_u0.z, Ef[32 + 4*_cb + 2], _aQ0);              \
        _aP0 = fmaf(_u0.w, Ef[4*_cb + 3], _aP0);                   \
        _aQ0 = fmaf(_u0.w, Ef[32 + 4*_cb + 3], _aQ0);              \
        _aP1 = fmaf(_u1.x, Ef[4*_cb + 4], _aP1);                   \
        _aQ1 = fmaf(_u1.x, Ef[32 + 4*_cb + 4], _aQ1);              \
        _aP1 = fmaf(_u1.y, Ef[4*_cb + 5], _aP1);                   \
        _aQ1 = fmaf(_u1.y, Ef[32 + 4*_cb + 5], _aQ1);              \
        _aP1 = fmaf(_u1.z, Ef[4*_cb + 6], _aP1);                   \
        _aQ1 = fmaf(_u1.z, Ef[32 + 4*_cb + 6], _aQ1);              \
        _aP1 = fmaf(_u1.w, Ef[4*_cb + 7], _aP1);                   \
        _aQ1 = fmaf(_u1.w, Ef[32 + 4*_cb + 7], _aQ1);              \
    }                                                              \
    float _aP = _aP0 + _aP1, _aQ = _aQ0 + _aQ1;                    \
    float _u = lo32 ? _aP : _aQ;                                   \
    float _w = lo32 ? _aQ : _aP;                                   \
    float _s = _u + __shfl_xor(_w, 32);                            \
    q = (BWDV) ? _s : ((EXV) * _s);                                \
} while (0)

// clamped row index: keeps every prefetch load unconditional + in-bounds
__device__ __forceinline__ int clamp_row(int tt, int Lm1) {
    return tt < 0 ? 0 : (tt > Lm1 ? Lm1 : tt);
}

template <bool FULL>
__global__ __launch_bounds__(64, 1) void crf_fwdbwd(
    const float* __restrict__ inputs, const float* __restrict__ trans,
    const int* __restrict__ tags, const int* __restrict__ lens,
    float* __restrict__ ws, float* __restrict__ out)
{
    const int j = threadIdx.x;
    const int g = j >> 5;            // input K-half this lane reads
    const int p = j & 31;
    const bool lo32 = (j < 32);
    const bool bwd = (!FULL) && (blockIdx.x >= Bn);
    const int b = bwd ? (blockIdx.x - Bn) : blockIdx.x;
    const int L = lens[b];
    const int Lm1 = L - 1;
    const float* inb = inputs + (size_t)b * Tn * Nn;

    // --- fused unary+binary score (fwd blocks only): 16 independent gather
    // iterations, issued before E-setup so latency hides under the setup +
    // recursion start. All loads unconditional+in-bounds; contribution
    // predicated on t < L. ---
    float sacc = 0.f;
    if (!bwd) {
        const int* tagb = tags + b * Tn;
        #pragma unroll
        for (int i = 0; i < Tn / 64; ++i) {
            int t  = j + 64 * i;
            int tm = t > 0 ? t - 1 : 0;
            int tg = tagb[t];
            int tp = tagb[tm];
            float un = inb[t * Nn + tg];
            float bi = trans[tp * Nn + tg];
            float c  = un + ((t >= 1) ? bi : 0.f);
            sacc += (t < L) ? c : 0.f;
        }
    }

    // Ef[c]    : weight of input (g*32+c) -> output p
    // Ef[32+c] : weight of input (g*32+c) -> output p+32
    float Ef[64];
    __shared__ float trsh[64 * 65];
    __shared__ __align__(16) float shq[64];
    if (!bwd) {
        // fwd: E[i][o] = exp(trans[i*64+o])
        #pragma unroll
        for (int c = 0; c < 32; ++c) {
            Ef[c]      = exp2f(trans[(g * 32 + c) * 64 + p     ] * LOG2E_F);
            Ef[32 + c] = exp2f(trans[(g * 32 + c) * 64 + p + 32] * LOG2E_F);
        }
    } else {
        // bwd: E[o][i] = exp(trans[o*64+i]); transpose-gather via LDS
        #pragma unroll
        for (int i = 0; i < 64; ++i) trsh[i * 65 + j] = trans[i * 64 + j];
        __syncthreads();
        #pragma unroll
        for (int c = 0; c < 32; ++c) {
            Ef[c]      = exp2f(trsh[p        * 65 + g * 32 + c] * LOG2E_F);
            Ef[32 + c] = exp2f(trsh[(p + 32) * 65 + g * 32 + c] * LOG2E_F);
        }
    }

    float q, base;
    int t0, dir, n;
    const int tf = L >> 1;           // forward covers t in [1,tf], backward (tf, L-1]
    if (!bwd) {
        float x0 = inb[j];
        float m = wave_max(x0);
        q = exp2f((x0 - m) * LOG2E_F);
        base = m;
        t0 = 1; dir = 1;
        n = FULL ? (L - 1) : tf;
    } else {
        q = 1.f; base = 0.f;
        t0 = L - 1; dir = -1;
        n = (L - 1) - tf;
    }

    // current 8-row register buffer (unconditional clamped loads)
    float xc[8];
    #pragma unroll
    for (int d = 0; d < 8; ++d)
        xc[d] = inb[clamp_row(t0 + d * dir, Lm1) * Nn + j];

    int t = t0;
    int k = 0;
    float pend = 1.0f;               // deferred 1/m from previous superstep

    if (!bwd) {
        while (k + 8 <= n) {
            float xn[8];
            #pragma unroll
            for (int d = 0; d < 8; ++d)
                xn[d] = inb[clamp_row(t + (8 + d) * dir, Lm1) * Nn + j];
            float exc[8];
            #pragma unroll
            for (int u = 0; u < 8; ++u)
                exc[u] = exp2f(fmaf(xc[u], LOG2E_F, -6.0f));
            exc[2] *= pend;          // apply deferred renorm off the chain
            #pragma unroll
            for (int u = 0; u < 8; ++u) STEP2(false, exc[u]);
            float m = wave_max(q);   // latency hides under next superstep
            base += __logf(m);
            pend = 1.0f / m;
            #pragma unroll
            for (int d = 0; d < 8; ++d) xc[d] = xn[d];
            k += 8; t += 8;
        }
        q *= pend; pend = 1.0f;
        #pragma unroll
        for (int u = 0; u < 8; ++u) {
            if (k + u < n) {
                float exu = exp2f(fmaf(xc[u], LOG2E_F, -6.0f));
                STEP2(false, exu);
            }
        }
    } else {
        while (k + 8 <= n) {
            float xn[8];
            #pragma unroll
            for (int d = 0; d < 8; ++d)
                xn[d] = inb[clamp_row(t - (8 + d), Lm1) * Nn + j];
            float exc[8];
            #pragma unroll
            for (int u = 0; u < 8; ++u)
                exc[u] = exp2f(fmaf(xc[u], LOG2E_F, -6.0f));
            exc[2] *= pend;
            #pragma unroll
            for (int u = 0; u < 8; ++u) STEP2(true, exc[u]);
            float m = wave_max(q);
            base += __logf(m);
            pend = 1.0f / m;
            #pragma unroll
            for (int d = 0; d < 8; ++d) xc[d] = xn[d];
            k += 8; t -= 8;
        }
        q *= pend; pend = 1.0f;
        #pragma unroll
        for (int u = 0; u < 8; ++u) {
            if (k + u < n) {
                float exu = exp2f(fmaf(xc[u], LOG2E_F, -6.0f));
                STEP2(true, exu);
            }
        }
    }

    // final renorm + account for the per-step 1/64 scaling
    {
        float m = wave_max(q);
        q *= (1.0f / m);
        base += __logf(m) + LN2_F * 6.0f * (float)n;
    }

    if (FULL) {
        float ssum = wave_sum(q);
        float sc = wave_sum(sacc);
        if (j == 0) out[b] = sc - (base + __logf(ssum));
    } else {
        float* fvec = ws;
        float* gvec = ws + Bn * 64;
        float* fb   = ws + 2 * Bn * 64;
        float* gb   = fb + Bn;
        if (!bwd) {
            float sc = wave_sum(sacc);
            fvec[b * 64 + j] = q;
            if (j == 0) { fb[b] = base; out[b] = sc; }
        } else {
            gvec[b * 64 + j] = q;
            if (j == 0) gb[b] = base;
        }
    }
}

// ---------------------------------------------------------------------------
// combine halves: logZ = log(f . g) + fbase + gbase; out[b] -= logZ
// ---------------------------------------------------------------------------
__global__ __launch_bounds__(64, 1) void crf_combine(
    const float* __restrict__ ws, float* __restrict__ out)
{
    const int b = blockIdx.x;
    const int j = threadIdx.x;
    const float* fvec = ws;
    const float* gvec = ws + Bn * 64;
    const float* fb   = ws + 2 * Bn * 64;
    const float* gb   = fb + Bn;

    float p = wave_sum(fvec[b * 64 + j] * gvec[b * 64 + j]);
    if (j == 0) out[b] -= (__logf(p) + fb[b] + gb[b]);
}

extern "C" void kernel_launch(void* const* d_in, const int* in_sizes, int n_in,
                              void* d_out, int out_size, void* d_ws, size_t ws_size,
                              hipStream_t stream) {
    const float* inputs = (const float*)d_in[0];
    const float* trans  = (const float*)d_in[1];
    const int*   tags   = (const int*)d_in[2];
    const int*   lens   = (const int*)d_in[3];
    float* out = (float*)d_out;
    float* ws  = (float*)d_ws;

    const size_t need = (size_t)(2 * Bn * 64 + 2 * Bn) * sizeof(float);
    if (ws_size >= need) {
        crf_fwdbwd<false><<<2 * Bn, 64, 0, stream>>>(inputs, trans, tags, lens, ws, out);
        crf_combine<<<Bn, 64, 0, stream>>>(ws, out);
    } else {
        // workspace too small: single-direction fallback (slower, no ws needed)
        crf_fwdbwd<true><<<Bn, 64, 0, stream>>>(inputs, trans, tags, lens, ws, out);
    }
}

// Round 7
// 314.700 us; speedup vs baseline: 1.0050x; 1.0050x over previous
//
#include <hip/hip_runtime.h>
#include <math.h>

#define Bn 512
#define Tn 1024
#define Nn 64
#define LOG2E_F 1.44269504088896340736f
#define LN2_F   0.69314718055994530942f

__device__ __forceinline__ float wave_max(float v) {
    #pragma unroll
    for (int o = 32; o > 0; o >>= 1) v = fmaxf(v, __shfl_xor(v, o));
    return v;
}
__device__ __forceinline__ float wave_sum(float v) {
    #pragma unroll
    for (int o = 32; o > 0; o >>= 1) v += __shfl_xor(v, o);
    return v;
}

// ---------------------------------------------------------------------------
// Main kernel, role by blockIdx:
//   [0, Bn)        forward half of the recursion  (writes fvec, fb)
//   [Bn, 2Bn)      backward half                   (writes gvec, gb)
//   [2Bn, 3Bn)     unary+binary scores             (writes out[b])
// R6 post-mortem: inlining scores into fwd blocks put the gather chains ON
// the critical-path block (+38us, 146.6->184.5). Scores as separate blocks
// of the SAME dispatch fill the idle wave slots (VALUBusy 24%, 1 wave/SIMD)
// and run concurrently with the stalled recursion waves instead.
// The ~127us total-vs-dispatch gap is harness restore overhead (constant
// across R1-R6) -- kernel budget is only the dispatches themselves.
//
// Serial-chain budget (R4: 687 cyc/step, VALUBusy 24%):
//   ds_write->ds_read data ~140 | 8x ds_read_b128 pipe ~100 |
//   64 FMA issue ~128 | shfl_xor(32) ~110 | mul/exp/misc ~100-200
// ---------------------------------------------------------------------------

// one recursion step; exact fp32. Single wave: LDS queue is in-order per
// wave, so write -> reads needs no barrier. (R4-measured-best form.)
#define STEP2(BWDV, EXV) do {                                      \
    shq[j] = (BWDV) ? ((EXV) * q) : q;                             \
    float4 _qv[8];                                                 \
    _Pragma("unroll")                                              \
    for (int _cb = 0; _cb < 8; ++_cb)                              \
        _qv[_cb] = *(const float4*)&shq[(g << 5) + (_cb << 2)];    \
    float _aP0 = 0.f, _aP1 = 0.f, _aQ0 = 0.f, _aQ1 = 0.f;         \
    _Pragma("unroll")                                              \
    for (int _cb = 0; _cb < 8; _cb += 2) {                         \
        const float4 _u0 = _qv[_cb], _u1 = _qv[_cb + 1];           \
        _aP0 = fmaf(_u0.x, Ef[4*_cb + 0], _aP0);                   \
        _aQ0 = fmaf(_u0.x, Ef[32 + 4*_cb + 0], _aQ0);              \
        _aP0 = fmaf(_u0.y, Ef[4*_cb + 1], _aP0);                   \
        _aQ0 = fmaf(_u0.y, Ef[32 + 4*_cb + 1], _aQ0);              \
        _aP0 = fmaf(_u0.z, Ef[4*_cb + 2], _aP0);                   \
        _aQ0 = fmaf(_u0.z, Ef[32 + 4*_cb + 2], _aQ0);              \
        _aP0 = fmaf(_u0.w, Ef[4*_cb + 3], _aP0);                   \
        _aQ0 = fmaf(_u0.w, Ef[32 + 4*_cb + 3], _aQ0);              \
        _aP1 = fmaf(_u1.x, Ef[4*_cb + 4], _aP1);                   \
        _aQ1 = fmaf(_u1.x, Ef[32 + 4*_cb + 4], _aQ1);              \
        _aP1 = fmaf(_u1.y, Ef[4*_cb + 5], _aP1);                   \
        _aQ1 = fmaf(_u1.y, Ef[32 + 4*_cb + 5], _aQ1);              \
        _aP1 = fmaf(_u1.z, Ef[4*_cb + 6], _aP1);                   \
        _aQ1 = fmaf(_u1.z, Ef[32 + 4*_cb + 6], _aQ1);              \
        _aP1 = fmaf(_u1.w, Ef[4*_cb + 7], _aP1);                   \
        _aQ1 = fmaf(_u1.w, Ef[32 + 4*_cb + 7], _aQ1);              \
    }                                                              \
    float _aP = _aP0 + _aP1, _aQ = _aQ0 + _aQ1;                    \
    float _u = lo32 ? _aP : _aQ;                                   \
    float _w = lo32 ? _aQ : _aP;                                   \
    float _s = _u + __shfl_xor(_w, 32);                            \
    q = (BWDV) ? _s : ((EXV) * _s);                                \
} while (0)

// clamped row index: keeps every prefetch load unconditional + in-bounds
__device__ __forceinline__ int clamp_row(int tt, int Lm1) {
    return tt < 0 ? 0 : (tt > Lm1 ? Lm1 : tt);
}

template <bool FULL>
__global__ __launch_bounds__(64, 1) void crf_main(
    const float* __restrict__ inputs, const float* __restrict__ trans,
    const int* __restrict__ tags, const int* __restrict__ lens,
    float* __restrict__ ws, float* __restrict__ out)
{
    const int j = threadIdx.x;

    // ---- score role: one wave per b, fills idle slots alongside recursion
    if (!FULL && blockIdx.x >= 2 * Bn) {
        const int b = blockIdx.x - 2 * Bn;
        const int L = lens[b];
        const int* tagb = tags + b * Tn;
        const float* inb = inputs + (size_t)b * Tn * Nn;
        float sacc = 0.f;
        #pragma unroll
        for (int i = 0; i < Tn / 64; ++i) {
            int t  = j + 64 * i;
            int tm = t > 0 ? t - 1 : 0;
            int tg = tagb[t];
            int tp = tagb[tm];
            float un = inb[t * Nn + tg];
            float bi = trans[tp * Nn + tg];
            float c  = un + ((t >= 1) ? bi : 0.f);
            sacc += (t < L) ? c : 0.f;
        }
        float sc = wave_sum(sacc);
        if (j == 0) out[b] = sc;
        return;
    }

    const int g = j >> 5;            // input K-half this lane reads
    const int p = j & 31;
    const bool lo32 = (j < 32);
    const bool bwd = (!FULL) && (blockIdx.x >= Bn);
    const int b = bwd ? (blockIdx.x - Bn) : blockIdx.x;
    const int L = lens[b];
    const int Lm1 = L - 1;
    const float* inb = inputs + (size_t)b * Tn * Nn;

    // Ef[c]    : weight of input (g*32+c) -> output p
    // Ef[32+c] : weight of input (g*32+c) -> output p+32
    float Ef[64];
    __shared__ float trsh[64 * 65];
    __shared__ __align__(16) float shq[64];
    if (!bwd) {
        // fwd: E[i][o] = exp(trans[i*64+o])
        #pragma unroll
        for (int c = 0; c < 32; ++c) {
            Ef[c]      = exp2f(trans[(g * 32 + c) * 64 + p     ] * LOG2E_F);
            Ef[32 + c] = exp2f(trans[(g * 32 + c) * 64 + p + 32] * LOG2E_F);
        }
    } else {
        // bwd: E[o][i] = exp(trans[o*64+i]); transpose-gather via LDS
        #pragma unroll
        for (int i = 0; i < 64; ++i) trsh[i * 65 + j] = trans[i * 64 + j];
        __syncthreads();
        #pragma unroll
        for (int c = 0; c < 32; ++c) {
            Ef[c]      = exp2f(trsh[p        * 65 + g * 32 + c] * LOG2E_F);
            Ef[32 + c] = exp2f(trsh[(p + 32) * 65 + g * 32 + c] * LOG2E_F);
        }
    }

    float q, base;
    int t0, dir, n;
    const int tf = L >> 1;           // forward covers t in [1,tf], backward (tf, L-1]
    if (!bwd) {
        float x0 = inb[j];
        float m = wave_max(x0);
        q = exp2f((x0 - m) * LOG2E_F);
        base = m;
        t0 = 1; dir = 1;
        n = FULL ? (L - 1) : tf;
    } else {
        q = 1.f; base = 0.f;
        t0 = L - 1; dir = -1;
        n = (L - 1) - tf;
    }

    // current 8-row register buffer (unconditional clamped loads)
    float xc[8];
    #pragma unroll
    for (int d = 0; d < 8; ++d)
        xc[d] = inb[clamp_row(t0 + d * dir, Lm1) * Nn + j];

    int t = t0;
    int k = 0;
    float pend = 1.0f;               // deferred 1/m from previous superstep

    if (!bwd) {
        while (k + 8 <= n) {
            float xn[8];
            #pragma unroll
            for (int d = 0; d < 8; ++d)
                xn[d] = inb[clamp_row(t + (8 + d) * dir, Lm1) * Nn + j];
            float exc[8];
            #pragma unroll
            for (int u = 0; u < 8; ++u)
                exc[u] = exp2f(fmaf(xc[u], LOG2E_F, -6.0f));
            exc[2] *= pend;          // apply deferred renorm off the chain
            #pragma unroll
            for (int u = 0; u < 8; ++u) STEP2(false, exc[u]);
            float m = wave_max(q);   // latency hides under next superstep
            base += __logf(m);
            pend = 1.0f / m;
            #pragma unroll
            for (int d = 0; d < 8; ++d) xc[d] = xn[d];
            k += 8; t += 8;
        }
        q *= pend; pend = 1.0f;
        #pragma unroll
        for (int u = 0; u < 8; ++u) {
            if (k + u < n) {
                float exu = exp2f(fmaf(xc[u], LOG2E_F, -6.0f));
                STEP2(false, exu);
            }
        }
    } else {
        while (k + 8 <= n) {
            float xn[8];
            #pragma unroll
            for (int d = 0; d < 8; ++d)
                xn[d] = inb[clamp_row(t - (8 + d), Lm1) * Nn + j];
            float exc[8];
            #pragma unroll
            for (int u = 0; u < 8; ++u)
                exc[u] = exp2f(fmaf(xc[u], LOG2E_F, -6.0f));
            exc[2] *= pend;
            #pragma unroll
            for (int u = 0; u < 8; ++u) STEP2(true, exc[u]);
            float m = wave_max(q);
            base += __logf(m);
            pend = 1.0f / m;
            #pragma unroll
            for (int d = 0; d < 8; ++d) xc[d] = xn[d];
            k += 8; t -= 8;
        }
        q *= pend; pend = 1.0f;
        #pragma unroll
        for (int u = 0; u < 8; ++u) {
            if (k + u < n) {
                float exu = exp2f(fmaf(xc[u], LOG2E_F, -6.0f));
                STEP2(true, exu);
            }
        }
    }

    // final renorm + account for the per-step 1/64 scaling
    {
        float m = wave_max(q);
        q *= (1.0f / m);
        base += __logf(m) + LN2_F * 6.0f * (float)n;
    }

    if (FULL) {
        float ssum = wave_sum(q);
        if (j == 0) out[b] -= (base + __logf(ssum));
    } else {
        float* fvec = ws;
        float* gvec = ws + Bn * 64;
        float* fb   = ws + 2 * Bn * 64;
        float* gb   = fb + Bn;
        if (!bwd) { fvec[b * 64 + j] = q; if (j == 0) fb[b] = base; }
        else      { gvec[b * 64 + j] = q; if (j == 0) gb[b] = base; }
    }
}

// ---------------------------------------------------------------------------
// scores standalone (fallback path only)
// ---------------------------------------------------------------------------
__global__ __launch_bounds__(256) void crf_scores(
    const float* __restrict__ inputs, const float* __restrict__ trans,
    const int* __restrict__ tags, const int* __restrict__ lens,
    float* __restrict__ out)
{
    const int b = blockIdx.x;
    const int L = lens[b];
    const int* tagb = tags + b * Tn;
    const float* inb = inputs + (size_t)b * Tn * Nn;

    float acc = 0.f;
    for (int t = threadIdx.x; t < L; t += 256) {
        int tg = tagb[t];
        acc += inb[t * Nn + tg];
        if (t >= 1) acc += trans[tagb[t - 1] * Nn + tg];
    }
    acc = wave_sum(acc);
    __shared__ float red[4];
    if ((threadIdx.x & 63) == 0) red[threadIdx.x >> 6] = acc;
    __syncthreads();
    if (threadIdx.x == 0) out[b] = (red[0] + red[1]) + (red[2] + red[3]);
}

// ---------------------------------------------------------------------------
// combine halves: logZ = log(f . g) + fbase + gbase; out[b] -= logZ
// ---------------------------------------------------------------------------
__global__ __launch_bounds__(64, 1) void crf_combine(
    const float* __restrict__ ws, float* __restrict__ out)
{
    const int b = blockIdx.x;
    const int j = threadIdx.x;
    const float* fvec = ws;
    const float* gvec = ws + Bn * 64;
    const float* fb   = ws + 2 * Bn * 64;
    const float* gb   = fb + Bn;

    float p = wave_sum(fvec[b * 64 + j] * gvec[b * 64 + j]);
    if (j == 0) out[b] -= (__logf(p) + fb[b] + gb[b]);
}

extern "C" void kernel_launch(void* const* d_in, const int* in_sizes, int n_in,
                              void* d_out, int out_size, void* d_ws, size_t ws_size,
                              hipStream_t stream) {
    const float* inputs = (const float*)d_in[0];
    const float* trans  = (const float*)d_in[1];
    const int*   tags   = (const int*)d_in[2];
    const int*   lens   = (const int*)d_in[3];
    float* out = (float*)d_out;
    float* ws  = (float*)d_ws;

    const size_t need = (size_t)(2 * Bn * 64 + 2 * Bn) * sizeof(float);
    if (ws_size >= need) {
        // fwd/bwd recursion blocks + concurrent score blocks in one dispatch
        crf_main<false><<<3 * Bn, 64, 0, stream>>>(inputs, trans, tags, lens, ws, out);
        crf_combine<<<Bn, 64, 0, stream>>>(ws, out);
    } else {
        // workspace too small: score kernel + single-direction fallback
        crf_scores<<<Bn, 256, 0, stream>>>(inputs, trans, tags, lens, out);
        crf_main<true><<<Bn, 64, 0, stream>>>(inputs, trans, tags, lens, ws, out);
    }
}